// Round 1
// baseline (85.068 us; speedup 1.0000x reference)
//
#include <hip/hip_runtime.h>

#define UNITS 256
#define BATCH 256

// Kernel 1: zero the output accumulator and compute segment-end prefix sums.
__global__ __launch_bounds__(256) void k_prep(const int* __restrict__ nclasses,
                                              const int* __restrict__ nfeature,
                                              int* __restrict__ ends,
                                              float* __restrict__ out) {
    const int t = threadIdx.x;
    const int b = blockIdx.x;
    // zero out[BATCH][UNITS]; grid is BATCH blocks x UNITS threads
    out[b * UNITS + t] = 0.0f;
    if (b == 0) {
        __shared__ int s[BATCH];
        s[t] = nclasses[t] * nfeature[t];
        __syncthreads();
        // Hillis-Steele inclusive scan (8 steps for 256)
        #pragma unroll
        for (int off = 1; off < BATCH; off <<= 1) {
            int v   = s[t];
            int add = (t >= off) ? s[t - off] : 0;
            __syncthreads();
            s[t] = v + add;
            __syncthreads();
        }
        ends[t] = s[t];  // inclusive cumsum: segment i covers [ends[i-1], ends[i])
    }
}

__device__ __forceinline__ void flush4(float* __restrict__ o, const float4& a) {
    unsafeAtomicAdd(o + 0, a.x);
    unsafeAtomicAdd(o + 1, a.y);
    unsafeAtomicAdd(o + 2, a.z);
    unsafeAtomicAdd(o + 3, a.w);
}

// Kernel 2: grid-stride chunked accumulation. Each block owns rows
// [blockIdx.x*rpb, ...+rpb). 4 waves/block: wave rl handles rows r0+rl, +4, ...
// Each lane owns a 4-column slice (float4) -> fully coalesced 1KB/row/wave.
__global__ __launch_bounds__(256) void k_accum(const float* __restrict__ x,
                                               const int* __restrict__ ends,
                                               float* __restrict__ out,
                                               int total_rows, int rpb) {
    __shared__ int s_ends[BATCH];
    const int t = threadIdx.x;
    s_ends[t] = ends[t];
    __syncthreads();

    const int c  = (t & 63) << 2;   // column start (0,4,...,252)
    const int rl = t >> 6;          // row lane 0..3
    const int r0 = blockIdx.x * rpb;
    const int rend = min(r0 + rpb, total_rows);
    int r = r0 + rl;
    if (r >= rend) return;

    // binary search: first segment with end > r
    int lo = 0, hi = BATCH;
    while (lo < hi) {
        int mid = (lo + hi) >> 1;
        if (s_ends[mid] > r) hi = mid; else lo = mid + 1;
    }
    int seg = lo;
    int cur_end = s_ends[seg];

    float4 acc = make_float4(0.f, 0.f, 0.f, 0.f);
    for (; r < rend; r += 4) {
        if (r >= cur_end) {
            flush4(out + seg * UNITS + c, acc);
            acc = make_float4(0.f, 0.f, 0.f, 0.f);
            while (s_ends[seg] <= r) ++seg;   // min segment = 100 rows, so ~1 step
            cur_end = s_ends[seg];
        }
        const float4 v = *reinterpret_cast<const float4*>(x + (size_t)r * UNITS + c);
        acc.x += v.x; acc.y += v.y; acc.z += v.z; acc.w += v.w;
    }
    flush4(out + seg * UNITS + c, acc);
}

// Kernel 3: divide each segment sum by its size.
__global__ __launch_bounds__(256) void k_div(const int* __restrict__ nclasses,
                                             const int* __restrict__ nfeature,
                                             float* __restrict__ out) {
    const int i = blockIdx.x;
    const int t = threadIdx.x;
    const float sz = (float)(nclasses[i] * nfeature[i]);
    out[i * UNITS + t] = out[i * UNITS + t] / sz;
}

extern "C" void kernel_launch(void* const* d_in, const int* in_sizes, int n_in,
                              void* d_out, int out_size, void* d_ws, size_t ws_size,
                              hipStream_t stream) {
    const float* x        = (const float*)d_in[0];
    const int*   nclasses = (const int*)d_in[1];
    const int*   nfeature = (const int*)d_in[2];
    float*       out      = (float*)d_out;
    int*         ends     = (int*)d_ws;   // 256 ints of scratch

    const int total_rows = in_sizes[0] / UNITS;

    // chunk rows so we get ~2048 blocks; round chunk up to multiple of 4
    int rpb = (total_rows + 2047) / 2048;
    rpb = (rpb + 3) & ~3;
    if (rpb < 4) rpb = 4;
    const int nblocks = (total_rows + rpb - 1) / rpb;

    k_prep<<<BATCH, UNITS, 0, stream>>>(nclasses, nfeature, ends, out);
    k_accum<<<nblocks, 256, 0, stream>>>(x, ends, out, total_rows, rpb);
    k_div<<<BATCH, UNITS, 0, stream>>>(nclasses, nfeature, out);
}

// Round 2
// 74.873 us; speedup vs baseline: 1.1362x; 1.1362x over previous
//
#include <hip/hip_runtime.h>

#define UNITS 256
#define BATCH 256

typedef float fx4 __attribute__((ext_vector_type(4)));

// Kernel 1: zero the output accumulator and compute segment-end prefix sums.
__global__ __launch_bounds__(256) void k_prep(const int* __restrict__ nclasses,
                                              const int* __restrict__ nfeature,
                                              int* __restrict__ ends,
                                              float* __restrict__ out) {
    const int t = threadIdx.x;
    const int b = blockIdx.x;
    out[b * UNITS + t] = 0.0f;
    if (b == 0) {
        __shared__ int s[BATCH];
        s[t] = nclasses[t] * nfeature[t];
        __syncthreads();
        #pragma unroll
        for (int off = 1; off < BATCH; off <<= 1) {
            int v   = s[t];
            int add = (t >= off) ? s[t - off] : 0;
            __syncthreads();
            s[t] = v + add;
            __syncthreads();
        }
        ends[t] = s[t];  // inclusive cumsum: segment i covers [ends[i-1], ends[i])
    }
}

// Kernel 2: chunked accumulation. Each block owns rows [blockIdx.x*rpb, +rpb).
// 4 waves/block: wave rl handles rows r0+rl, r0+rl+4, ... Each lane owns a
// 4-column float4 slice -> wave reads one contiguous 1KB row per load instr.
// Inner loop is branch-free between segment boundaries (cnt hoisted), manually
// unrolled x4 for 4 outstanding loads/lane; nontemporal (single-use stream).
// The per-segment divide is folded into the flush (acc * 1/size).
__global__ __launch_bounds__(256) void k_accum(const float* __restrict__ x,
                                               const int* __restrict__ ends,
                                               const int* __restrict__ nclasses,
                                               const int* __restrict__ nfeature,
                                               float* __restrict__ out,
                                               int total_rows, int rpb) {
    __shared__ int   s_ends[BATCH];
    __shared__ float s_inv[BATCH];
    const int t = threadIdx.x;
    s_ends[t] = ends[t];
    s_inv[t]  = 1.0f / (float)(nclasses[t] * nfeature[t]);
    __syncthreads();

    const int c    = (t & 63) << 2;   // column start (0,4,...,252)
    const int rl   = t >> 6;          // wave id 0..3 = row lane
    const int r0   = blockIdx.x * rpb;
    const int rend = min(r0 + rpb, total_rows);
    int r = r0 + rl;
    if (r >= rend) return;

    // binary search: first segment with end > r (wave-uniform -> LDS broadcast)
    int lo = 0, hi = BATCH;
    while (lo < hi) {
        int mid = (lo + hi) >> 1;
        if (s_ends[mid] > r) hi = mid; else lo = mid + 1;
    }
    int seg = lo;

    fx4 acc = {0.f, 0.f, 0.f, 0.f};
    const float* p = x + (size_t)r * UNITS + c;

    for (;;) {
        const int stop = min(s_ends[seg], rend);
        int cnt = (stop - r + 3) >> 2;   // rows this lane accumulates in [r, stop)
        r += cnt << 2;
        int k = 0;
        for (; k + 4 <= cnt; k += 4) {
            fx4 v0 = __builtin_nontemporal_load((const fx4*)(p));
            fx4 v1 = __builtin_nontemporal_load((const fx4*)(p + 4 * UNITS));
            fx4 v2 = __builtin_nontemporal_load((const fx4*)(p + 8 * UNITS));
            fx4 v3 = __builtin_nontemporal_load((const fx4*)(p + 12 * UNITS));
            p += 16 * UNITS;
            acc += (v0 + v1) + (v2 + v3);
        }
        for (; k < cnt; ++k) {
            fx4 v = __builtin_nontemporal_load((const fx4*)(p));
            p += 4 * UNITS;
            acc += v;
        }
        // flush this segment's partial, scaled by 1/size (replaces k_div)
        {
            const float s = s_inv[seg];
            float* o = out + seg * UNITS + c;
            unsafeAtomicAdd(o + 0, acc.x * s);
            unsafeAtomicAdd(o + 1, acc.y * s);
            unsafeAtomicAdd(o + 2, acc.z * s);
            unsafeAtomicAdd(o + 3, acc.w * s);
        }
        if (r >= rend) break;
        acc = fx4{0.f, 0.f, 0.f, 0.f};
        while (s_ends[seg] <= r) ++seg;  // segments are >=100 rows: ~1 step
    }
}

extern "C" void kernel_launch(void* const* d_in, const int* in_sizes, int n_in,
                              void* d_out, int out_size, void* d_ws, size_t ws_size,
                              hipStream_t stream) {
    const float* x        = (const float*)d_in[0];
    const int*   nclasses = (const int*)d_in[1];
    const int*   nfeature = (const int*)d_in[2];
    float*       out      = (float*)d_out;
    int*         ends     = (int*)d_ws;   // 256 ints of scratch

    const int total_rows = in_sizes[0] / UNITS;

    int rpb = (total_rows + 2047) / 2048;
    rpb = (rpb + 3) & ~3;
    if (rpb < 4) rpb = 4;
    const int nblocks = (total_rows + rpb - 1) / rpb;

    k_prep<<<BATCH, UNITS, 0, stream>>>(nclasses, nfeature, ends, out);
    k_accum<<<nblocks, 256, 0, stream>>>(x, ends, nclasses, nfeature, out,
                                         total_rows, rpb);
}

// Round 3
// 56.274 us; speedup vs baseline: 1.5117x; 1.3305x over previous
//
#include <hip/hip_runtime.h>

#define UNITS 256
#define BATCH 256

typedef float fx4 __attribute__((ext_vector_type(4)));

// Kernel 1: zero the output accumulator and compute segment-end prefix sums.
__global__ __launch_bounds__(256) void k_prep(const int* __restrict__ nclasses,
                                              const int* __restrict__ nfeature,
                                              int* __restrict__ ends,
                                              float* __restrict__ out) {
    const int t = threadIdx.x;
    const int b = blockIdx.x;
    out[b * UNITS + t] = 0.0f;
    if (b == 0) {
        __shared__ int s[BATCH];
        s[t] = nclasses[t] * nfeature[t];
        __syncthreads();
        #pragma unroll
        for (int off = 1; off < BATCH; off <<= 1) {
            int v   = s[t];
            int add = (t >= off) ? s[t - off] : 0;
            __syncthreads();
            s[t] = v + add;
            __syncthreads();
        }
        ends[t] = s[t];  // inclusive cumsum: segment i covers [ends[i-1], ends[i])
    }
}

// Kernel 2: chunked accumulation with BLOCK-UNIFORM segment walk.
// Each block owns rows [blockIdx.x*rpb, +rpb). Wave rl covers rows r0+rl,
// r0+rl+4, ...; each lane owns a 4-column float4 slice (wave = contiguous
// 1KB row read). Every wave visits every segment intersecting the chunk
// (cnt clamps to 0), so flush points are block-synchronous: waves 1-3
// deposit partials in LDS, wave 0 reduces and issues ONE atomic flush per
// block per segment (4x fewer atomics, no intra-block same-address storms).
// Per-segment divide folded into the flush.
__global__ __launch_bounds__(256) void k_accum(const float* __restrict__ x,
                                               const int* __restrict__ ends,
                                               const int* __restrict__ nclasses,
                                               const int* __restrict__ nfeature,
                                               float* __restrict__ out,
                                               int total_rows, int rpb) {
    __shared__ int   s_ends[BATCH];
    __shared__ float s_inv[BATCH];
    __shared__ fx4   s_red[3][64];
    const int t  = threadIdx.x;
    const int ln = t & 63;
    const int rl = t >> 6;
    s_ends[t] = ends[t];
    s_inv[t]  = 1.0f / (float)(nclasses[t] * nfeature[t]);
    __syncthreads();

    const int c    = ln << 2;             // column start (0,4,...,252)
    const int r0   = blockIdx.x * rpb;
    const int rend = min(r0 + rpb, total_rows);
    if (r0 >= total_rows) return;         // block-uniform

    // block-uniform binary search: first segment with end > r0
    int lo = 0, hi = BATCH;
    while (lo < hi) {
        int mid = (lo + hi) >> 1;
        if (s_ends[mid] > r0) hi = mid; else lo = mid + 1;
    }
    int seg = lo;

    int r = r0 + rl;                      // per-wave row cursor
    const float* p = x + (size_t)r * UNITS + c;

    for (;;) {
        const int stop = min(s_ends[seg], rend);
        int cnt = (stop - r + 3) >> 2;    // this wave's rows in [r, stop)
        if (cnt < 0) cnt = 0;
        r += cnt << 2;

        fx4 acc = {0.f, 0.f, 0.f, 0.f};
        int k = 0;
        for (; k + 4 <= cnt; k += 4) {    // 4 outstanding 16B loads/lane
            fx4 v0 = *(const fx4*)(p);
            fx4 v1 = *(const fx4*)(p + 4 * UNITS);
            fx4 v2 = *(const fx4*)(p + 8 * UNITS);
            fx4 v3 = *(const fx4*)(p + 12 * UNITS);
            p += 16 * UNITS;
            acc += (v0 + v1) + (v2 + v3);
        }
        for (; k < cnt; ++k) {
            fx4 v = *(const fx4*)(p);
            p += 4 * UNITS;
            acc += v;
        }

        // cross-wave reduce: waves 1-3 -> LDS, wave 0 flushes once
        if (rl) s_red[rl - 1][ln] = acc;
        __syncthreads();
        if (rl == 0) {
            acc += s_red[0][ln];
            acc += s_red[1][ln];
            acc += s_red[2][ln];
            const float s = s_inv[seg];
            float* o = out + seg * UNITS + c;
            unsafeAtomicAdd(o + 0, acc.x * s);
            unsafeAtomicAdd(o + 1, acc.y * s);
            unsafeAtomicAdd(o + 2, acc.z * s);
            unsafeAtomicAdd(o + 3, acc.w * s);
        }
        if (s_ends[seg] >= rend) break;   // last intersecting segment: uniform
        ++seg;
        __syncthreads();                  // protect s_red reuse
    }
}

extern "C" void kernel_launch(void* const* d_in, const int* in_sizes, int n_in,
                              void* d_out, int out_size, void* d_ws, size_t ws_size,
                              hipStream_t stream) {
    const float* x        = (const float*)d_in[0];
    const int*   nclasses = (const int*)d_in[1];
    const int*   nfeature = (const int*)d_in[2];
    float*       out      = (float*)d_out;
    int*         ends     = (int*)d_ws;   // 256 ints of scratch

    const int total_rows = in_sizes[0] / UNITS;

    int rpb = (total_rows + 2047) / 2048;
    rpb = (rpb + 3) & ~3;
    if (rpb < 4) rpb = 4;
    const int nblocks = (total_rows + rpb - 1) / rpb;

    k_prep<<<BATCH, UNITS, 0, stream>>>(nclasses, nfeature, ends, out);
    k_accum<<<nblocks, 256, 0, stream>>>(x, ends, nclasses, nfeature, out,
                                         total_rows, rpb);
}